// Round 1
// baseline (729.498 us; speedup 1.0000x reference)
//
#include <hip/hip_runtime.h>
#include <math.h>

#define N_NODES 50000
#define N_EDGES 800000
#define D 64
#define N_GRAPHS 512
#define N_LAYERS 3
#define HID_FC 64
#define N_CLASSES 10

// ---------------- helpers ----------------

// order-preserving float->uint mapping for atomicMax on signed floats
__device__ __forceinline__ unsigned mapf(float f) {
  unsigned u = __float_as_uint(f);
  return (u & 0x80000000u) ? ~u : (u | 0x80000000u);
}
__device__ __forceinline__ float unmapf(unsigned u) {
  return __uint_as_float((u & 0x80000000u) ? (u & 0x7FFFFFFFu) : ~u);
}

// ---------------- kernels ----------------

__global__ void copy_f4(const float* __restrict__ in, float* __restrict__ out, int n4) {
  int i = blockIdx.x * blockDim.x + threadIdx.x;
  if (i < n4) reinterpret_cast<float4*>(out)[i] = reinterpret_cast<const float4*>(in)[i];
}

// acc[dst[e]][d] += h[src[e]][d]; one thread per (edge, dim)
__global__ void scatter_add(const float* __restrict__ h,
                            const int* __restrict__ src,
                            const int* __restrict__ dst,
                            float* __restrict__ acc) {
  long long idx = (long long)blockIdx.x * blockDim.x + threadIdx.x;
  if (idx >= (long long)N_EDGES * D) return;
  int e = (int)(idx >> 6);
  int d = (int)(idx & 63);
  int s = src[e];
  int t = dst[e];
  atomicAdd(&acc[(long long)t * D + d], h[(long long)s * D + d]);
}

// C[r][c] = (relu?)( sum_k A[r][k] * W[k][c] + b[c] ), A: nrows x 64, W: 64x64
template <bool RELU>
__global__ void gemm64(const float* __restrict__ A, const float* __restrict__ W,
                       const float* __restrict__ b, float* __restrict__ C, int nrows) {
  __shared__ float Ws[64][64];
  __shared__ float As[4][64];
  const int tx = threadIdx.x;  // 0..63 (output column)
  const int ty = threadIdx.y;  // 0..3  (row within block)
  const int tid = ty * 64 + tx;
  for (int i = tid; i < 64 * 64; i += 256) Ws[i >> 6][i & 63] = W[i];
  const int row = blockIdx.x * 4 + ty;
  if (row < nrows) As[ty][tx] = A[row * 64 + tx];
  __syncthreads();
  if (row < nrows) {
    float acc = b[tx];
#pragma unroll
    for (int k = 0; k < 64; ++k) acc = fmaf(As[ty][k], Ws[k][tx], acc);
    if (RELU) acc = fmaxf(acc, 0.0f);
    C[row * 64 + tx] = acc;
  }
}

__global__ void init_g(unsigned* __restrict__ gU) {
  int i = blockIdx.x * blockDim.x + threadIdx.x;
  if (i < N_GRAPHS * D) gU[i] = 0x007FFFFFu;  // mapf(-inf)
}

__global__ void seg_max(const float* __restrict__ h, const int* __restrict__ batch,
                        unsigned* __restrict__ gU) {
  int idx = blockIdx.x * blockDim.x + threadIdx.x;
  if (idx >= N_NODES * D) return;
  int n = idx >> 6;
  int d = idx & 63;
  atomicMax(&gU[batch[n] * D + d], mapf(h[idx]));
}

// one block (64 threads) per graph: FC(64->64) relu, FC(64->10), log_softmax
__global__ void head_kernel(const unsigned* __restrict__ gU,
                            const float* __restrict__ fcW1, const float* __restrict__ fcb1,
                            const float* __restrict__ fcW2, const float* __restrict__ fcb2,
                            float* __restrict__ out) {
  __shared__ float g[64];
  __shared__ float hid[64];
  __shared__ float logit[N_CLASSES];
  __shared__ float red[2];
  const int gi = blockIdx.x;
  const int t = threadIdx.x;

  g[t] = unmapf(gU[gi * D + t]);
  __syncthreads();

  float a = fcb1[t];
#pragma unroll
  for (int k = 0; k < 64; ++k) a = fmaf(g[k], fcW1[k * HID_FC + t], a);
  hid[t] = fmaxf(a, 0.0f);
  __syncthreads();

  if (t < N_CLASSES) {
    float l = fcb2[t];
#pragma unroll
    for (int k = 0; k < 64; ++k) l = fmaf(hid[k], fcW2[k * N_CLASSES + t], l);
    logit[t] = l;
  }
  __syncthreads();

  if (t == 0) {
    float m = logit[0];
    for (int i = 1; i < N_CLASSES; ++i) m = fmaxf(m, logit[i]);
    float s = 0.0f;
    for (int i = 0; i < N_CLASSES; ++i) s += expf(logit[i] - m);
    red[0] = m;
    red[1] = logf(s);
  }
  __syncthreads();

  if (t < N_CLASSES) out[gi * N_CLASSES + t] = logit[t] - red[0] - red[1];
}

// ---------------- launch ----------------

extern "C" void kernel_launch(void* const* d_in, const int* in_sizes, int n_in,
                              void* d_out, int out_size, void* d_ws, size_t ws_size,
                              hipStream_t stream) {
  const float* x      = (const float*)d_in[0];
  const float* convW1 = (const float*)d_in[1];
  const float* convb1 = (const float*)d_in[2];
  const float* convW2 = (const float*)d_in[3];
  const float* convb2 = (const float*)d_in[4];
  const float* fcW1   = (const float*)d_in[5];
  const float* fcb1   = (const float*)d_in[6];
  const float* fcW2   = (const float*)d_in[7];
  const float* fcb2   = (const float*)d_in[8];
  const int*   edge   = (const int*)d_in[9];
  const int*   batch  = (const int*)d_in[10];
  float* out = (float*)d_out;

  const int* src = edge;            // edge_index[0]
  const int* dst = edge + N_EDGES;  // edge_index[1]

  float* A = (float*)d_ws;
  float* B = A + (size_t)N_NODES * D;
  unsigned* gU = (unsigned*)(B + (size_t)N_NODES * D);

  const int nElem = N_NODES * D;                       // 3.2M
  const int copyBlocks = (nElem / 4 + 255) / 256;      // float4 copy
  const long long scatterThreads = (long long)N_EDGES * D;
  const int scatterBlocks = (int)((scatterThreads + 255) / 256);
  const int gemmBlocks = (N_NODES + 3) / 4;

  const float* h = x;
  for (int l = 0; l < N_LAYERS; ++l) {
    float* acc = (l % 2 == 0) ? A : B;
    float* oth = (l % 2 == 0) ? B : A;

    // acc = h ; acc[dst] += h[src]
    copy_f4<<<copyBlocks, 256, 0, stream>>>(h, acc, nElem / 4);
    scatter_add<<<scatterBlocks, 256, 0, stream>>>(h, src, dst, acc);
    // oth = relu(acc @ W1 + b1)
    gemm64<true><<<gemmBlocks, dim3(64, 4), 0, stream>>>(
        acc, convW1 + (size_t)l * D * D, convb1 + (size_t)l * D, oth, N_NODES);
    // acc = oth @ W2 + b2   (acc already consumed; safe to overwrite)
    gemm64<false><<<gemmBlocks, dim3(64, 4), 0, stream>>>(
        oth, convW2 + (size_t)l * D * D, convb2 + (size_t)l * D, acc, N_NODES);
    h = acc;
  }

  // global max pool
  init_g<<<(N_GRAPHS * D + 255) / 256, 256, 0, stream>>>(gU);
  seg_max<<<(nElem + 255) / 256, 256, 0, stream>>>(h, batch, gU);

  // FC head + log_softmax
  head_kernel<<<N_GRAPHS, 64, 0, stream>>>(gU, fcW1, fcb1, fcW2, fcb2, out);
}

// Round 2
// 297.128 us; speedup vs baseline: 2.4552x; 2.4552x over previous
//
#include <hip/hip_runtime.h>
#include <math.h>

#define N_NODES 50000
#define N_EDGES 800000
#define D 64
#define N_GRAPHS 512
#define N_LAYERS 3
#define HID_FC 64
#define N_CLASSES 10

#define SCAN_B 512
#define NB_SCAN ((N_NODES + SCAN_B - 1) / SCAN_B)  // 98

// ---------------- helpers ----------------

__device__ __forceinline__ unsigned mapf(float f) {
  unsigned u = __float_as_uint(f);
  return (u & 0x80000000u) ? ~u : (u | 0x80000000u);
}
__device__ __forceinline__ float unmapf(unsigned u) {
  return __uint_as_float((u & 0x80000000u) ? (u & 0x7FFFFFFFu) : ~u);
}

// ---------------- CSR build ----------------

__global__ void hist_kernel(const int* __restrict__ dst, int* __restrict__ deg) {
  int e = blockIdx.x * 256 + threadIdx.x;
  if (e < N_EDGES) atomicAdd(&deg[dst[e]], 1);
}

__global__ void scan_blocks(const int* __restrict__ deg, int* __restrict__ bsum) {
  __shared__ int sd[SCAN_B];
  int i = blockIdx.x * SCAN_B + threadIdx.x;
  sd[threadIdx.x] = (i < N_NODES) ? deg[i] : 0;
  __syncthreads();
  for (int off = SCAN_B / 2; off > 0; off >>= 1) {
    if (threadIdx.x < off) sd[threadIdx.x] += sd[threadIdx.x + off];
    __syncthreads();
  }
  if (threadIdx.x == 0) bsum[blockIdx.x] = sd[0];
}

__global__ void scan_mid(int* __restrict__ bsum) {
  __shared__ int s[256];
  int t = threadIdx.x;
  if (t < NB_SCAN) s[t] = bsum[t];
  __syncthreads();
  if (t == 0) {
    int run = 0;
    for (int i = 0; i < NB_SCAN; ++i) { int v = s[i]; s[i] = run; run += v; }
  }
  __syncthreads();
  if (t < NB_SCAN) bsum[t] = s[t];
}

__global__ void scan_final(const int* __restrict__ deg, const int* __restrict__ bsum,
                           int* __restrict__ rs, int* __restrict__ cur) {
  __shared__ int sd[SCAN_B];
  int i = blockIdx.x * SCAN_B + threadIdx.x;
  int v = (i < N_NODES) ? deg[i] : 0;
  sd[threadIdx.x] = v;
  __syncthreads();
  // Hillis-Steele inclusive scan
  for (int off = 1; off < SCAN_B; off <<= 1) {
    int add = (threadIdx.x >= off) ? sd[threadIdx.x - off] : 0;
    __syncthreads();
    sd[threadIdx.x] += add;
    __syncthreads();
  }
  if (i < N_NODES) {
    int ex = bsum[blockIdx.x] + sd[threadIdx.x] - v;
    rs[i] = ex;
    cur[i] = ex;
  }
  if (i == 0) rs[N_NODES] = N_EDGES;
}

__global__ void fill_csr(const int* __restrict__ src, const int* __restrict__ dst,
                         int* __restrict__ cur, int* __restrict__ csr) {
  int e = blockIdx.x * 256 + threadIdx.x;
  if (e >= N_EDGES) return;
  int p = atomicAdd(&cur[dst[e]], 1);
  csr[p] = src[e];
}

// ---------------- GIN aggregation: acc[n] = h[n] + sum_{e in CSR[n]} h[src] ----------------

__global__ __launch_bounds__(256) void agg_kernel(const float* __restrict__ hin,
                                                  const int* __restrict__ csr,
                                                  const int* __restrict__ rs,
                                                  float* __restrict__ acc) {
  const int t = threadIdx.x;
  const int lane = t & 63;
  const int node = blockIdx.x * 4 + (t >> 6);
  float a = hin[node * 64 + lane];
  int e = rs[node];
  const int e1 = rs[node + 1];
  for (; e + 4 <= e1; e += 4) {
    int s0 = csr[e], s1 = csr[e + 1], s2 = csr[e + 2], s3 = csr[e + 3];
    float v0 = hin[s0 * 64 + lane];
    float v1 = hin[s1 * 64 + lane];
    float v2 = hin[s2 * 64 + lane];
    float v3 = hin[s3 * 64 + lane];
    a += v0; a += v1; a += v2; a += v3;
  }
  for (; e < e1; ++e) a += hin[csr[e] * 64 + lane];
  acc[node * 64 + lane] = a;
}

// ---------------- fused per-layer MLP (in-place): h = relu(h@W1+b1)@W2+b2 ----------------

__global__ __launch_bounds__(256) void mlp_kernel(float* __restrict__ A,
                                                  const float* __restrict__ W1,
                                                  const float* __restrict__ b1,
                                                  const float* __restrict__ W2,
                                                  const float* __restrict__ b2) {
  __shared__ float W1s[64 * 64];
  __shared__ float W2s[64 * 64];
  __shared__ float As[16][68];
  __shared__ float Hs[16][68];
  const int t = threadIdx.x;

  const float4* w1v = (const float4*)W1;
  const float4* w2v = (const float4*)W2;
  float4* w1s = (float4*)W1s;
  float4* w2s = (float4*)W2s;
#pragma unroll
  for (int i = 0; i < 4; ++i) {
    w1s[t + 256 * i] = w1v[t + 256 * i];
    w2s[t + 256 * i] = w2v[t + 256 * i];
  }

  const int r = t >> 4, cg = t & 15;
  const int row = blockIdx.x * 16 + r;
  float4 av = ((const float4*)(A + (size_t)row * 64))[cg];
  As[r][cg * 4 + 0] = av.x;
  As[r][cg * 4 + 1] = av.y;
  As[r][cg * 4 + 2] = av.z;
  As[r][cg * 4 + 3] = av.w;
  __syncthreads();

  float4 bb = ((const float4*)b1)[cg];
  float a0 = bb.x, a1 = bb.y, a2 = bb.z, a3 = bb.w;
#pragma unroll
  for (int k = 0; k < 64; ++k) {
    float x = As[r][k];
    float4 w = *(const float4*)&W1s[k * 64 + cg * 4];
    a0 = fmaf(x, w.x, a0);
    a1 = fmaf(x, w.y, a1);
    a2 = fmaf(x, w.z, a2);
    a3 = fmaf(x, w.w, a3);
  }
  Hs[r][cg * 4 + 0] = fmaxf(a0, 0.0f);
  Hs[r][cg * 4 + 1] = fmaxf(a1, 0.0f);
  Hs[r][cg * 4 + 2] = fmaxf(a2, 0.0f);
  Hs[r][cg * 4 + 3] = fmaxf(a3, 0.0f);
  __syncthreads();

  bb = ((const float4*)b2)[cg];
  a0 = bb.x; a1 = bb.y; a2 = bb.z; a3 = bb.w;
#pragma unroll
  for (int k = 0; k < 64; ++k) {
    float x = Hs[r][k];
    float4 w = *(const float4*)&W2s[k * 64 + cg * 4];
    a0 = fmaf(x, w.x, a0);
    a1 = fmaf(x, w.y, a1);
    a2 = fmaf(x, w.z, a2);
    a3 = fmaf(x, w.w, a3);
  }
  ((float4*)(A + (size_t)row * 64))[cg] = make_float4(a0, a1, a2, a3);
}

// ---------------- pooling + head ----------------

__global__ void init_g(unsigned* __restrict__ gU) {
  int i = blockIdx.x * blockDim.x + threadIdx.x;
  if (i < N_GRAPHS * D) gU[i] = 0x007FFFFFu;  // mapf(-inf)
}

__global__ void seg_max(const float* __restrict__ h, const int* __restrict__ batch,
                        unsigned* __restrict__ gU) {
  int idx = blockIdx.x * blockDim.x + threadIdx.x;
  if (idx >= N_NODES * D) return;
  int n = idx >> 6;
  int d = idx & 63;
  atomicMax(&gU[batch[n] * D + d], mapf(h[idx]));
}

__global__ void head_kernel(const unsigned* __restrict__ gU,
                            const float* __restrict__ fcW1, const float* __restrict__ fcb1,
                            const float* __restrict__ fcW2, const float* __restrict__ fcb2,
                            float* __restrict__ out) {
  __shared__ float g[64];
  __shared__ float hid[64];
  __shared__ float logit[N_CLASSES];
  __shared__ float red[2];
  const int gi = blockIdx.x;
  const int t = threadIdx.x;

  g[t] = unmapf(gU[gi * D + t]);
  __syncthreads();

  float a = fcb1[t];
#pragma unroll
  for (int k = 0; k < 64; ++k) a = fmaf(g[k], fcW1[k * HID_FC + t], a);
  hid[t] = fmaxf(a, 0.0f);
  __syncthreads();

  if (t < N_CLASSES) {
    float l = fcb2[t];
#pragma unroll
    for (int k = 0; k < 64; ++k) l = fmaf(hid[k], fcW2[k * N_CLASSES + t], l);
    logit[t] = l;
  }
  __syncthreads();

  if (t == 0) {
    float m = logit[0];
    for (int i = 1; i < N_CLASSES; ++i) m = fmaxf(m, logit[i]);
    float s = 0.0f;
    for (int i = 0; i < N_CLASSES; ++i) s += expf(logit[i] - m);
    red[0] = m;
    red[1] = logf(s);
  }
  __syncthreads();

  if (t < N_CLASSES) out[gi * N_CLASSES + t] = logit[t] - red[0] - red[1];
}

// ---------------- launch ----------------

extern "C" void kernel_launch(void* const* d_in, const int* in_sizes, int n_in,
                              void* d_out, int out_size, void* d_ws, size_t ws_size,
                              hipStream_t stream) {
  const float* x      = (const float*)d_in[0];
  const float* convW1 = (const float*)d_in[1];
  const float* convb1 = (const float*)d_in[2];
  const float* convW2 = (const float*)d_in[3];
  const float* convb2 = (const float*)d_in[4];
  const float* fcW1   = (const float*)d_in[5];
  const float* fcb1   = (const float*)d_in[6];
  const float* fcW2   = (const float*)d_in[7];
  const float* fcb2   = (const float*)d_in[8];
  const int*   edge   = (const int*)d_in[9];
  const int*   batch  = (const int*)d_in[10];
  float* out = (float*)d_out;

  const int* src = edge;
  const int* dst = edge + N_EDGES;

  float* A = (float*)d_ws;
  float* B = A + (size_t)N_NODES * D;
  unsigned* gU = (unsigned*)(B + (size_t)N_NODES * D);
  int* deg  = (int*)(gU + N_GRAPHS * D);
  int* rs   = deg + N_NODES;
  int* cur  = rs + N_NODES + 1;
  int* bsum = cur + N_NODES;
  int* csr  = bsum + 256;

  // ---- CSR build (dst-indexed), once per call ----
  hipMemsetAsync(deg, 0, N_NODES * sizeof(int), stream);
  hist_kernel<<<N_EDGES / 256, 256, 0, stream>>>(dst, deg);
  scan_blocks<<<NB_SCAN, SCAN_B, 0, stream>>>(deg, bsum);
  scan_mid<<<1, 256, 0, stream>>>(bsum);
  scan_final<<<NB_SCAN, SCAN_B, 0, stream>>>(deg, bsum, rs, cur);
  fill_csr<<<N_EDGES / 256, 256, 0, stream>>>(src, dst, cur, csr);

  // ---- 3 GIN layers ----
  const float* h = x;
  for (int l = 0; l < N_LAYERS; ++l) {
    float* acc = (l % 2 == 0) ? A : B;
    agg_kernel<<<N_NODES / 4, 256, 0, stream>>>(h, csr, rs, acc);
    mlp_kernel<<<N_NODES / 16, 256, 0, stream>>>(
        acc, convW1 + (size_t)l * D * D, convb1 + (size_t)l * D,
        convW2 + (size_t)l * D * D, convb2 + (size_t)l * D);
    h = acc;
  }

  // ---- global max pool ----
  init_g<<<(N_GRAPHS * D + 255) / 256, 256, 0, stream>>>(gU);
  seg_max<<<(N_NODES * D + 255) / 256, 256, 0, stream>>>(h, batch, gU);

  // ---- FC head + log_softmax ----
  head_kernel<<<N_GRAPHS, 64, 0, stream>>>(gU, fcW1, fcb1, fcW2, fcb2, out);
}